// Round 24
// baseline (584.958 us; speedup 1.0000x reference)
//
#include <hip/hip_runtime.h>
#include <hip/hip_bf16.h>
#include <math.h>

#define B_   32
#define C_   684
#define H_   28
#define W_   112
#define L_   3136      // H_*W_
#define Q_   256
#define NP_  512
#define N_   256
#define K_   11
#define KK_  121       // K_*K_
#define KI_  684       // K rows from i
#define KPATCH_ 805    // 684 + 121 (im2col of alpha)
#define KT_  832       // padded K = 13*64
#define KTILES_ 52     // KT_/16
#define BM_  32        // l rows per block (32 | L_, so block lies in one b)
#define KC_  64        // K chunk staged in LDS
#define NCH_ 13        // KT_/KC_

typedef short bf16x8  __attribute__((ext_vector_type(8)));
typedef float f32x16  __attribute__((ext_vector_type(16)));

#define MFMA32(a, b, c) __builtin_amdgcn_mfma_f32_32x32x16_bf16((a), (b), (c), 0, 0, 0)

// fp32 -> bf16 round-to-nearest-even (bit trick)
__device__ __forceinline__ unsigned short f2bf(float x) {
  unsigned u = __float_as_uint(x);
  u += 0x7FFF + ((u >> 16) & 1);
  return (unsigned short)(u >> 16);
}
// cast-path conversion (same RNE; compiler can emit v_cvt_pk_bf16_f32)
__device__ __forceinline__ short f2bf_fast(float x) {
  __hip_bfloat16 h = __float2bfloat16(x);
  return *reinterpret_cast<short*>(&h);
}

// ---------------------------------------------------------------------------
// Kernel A: hsb[b][p] = sum_n s[b][n]*Ws[n][p] + sum_q conv_b[q]*Wf[q][p]
// ---------------------------------------------------------------------------
__global__ __launch_bounds__(256) void k_hsb(const float* __restrict__ s,
                                             const float* __restrict__ Ws,
                                             const float* __restrict__ conv_b,
                                             const float* __restrict__ Wf,
                                             float* __restrict__ hsb) {
  int b = blockIdx.x, t = threadIdx.x;
  int p0 = t, p1 = t + 256;
  float a0 = 0.f, a1 = 0.f;
  for (int n = 0; n < N_; n++) {
    float sv = s[b * N_ + n];
    a0 += sv * Ws[n * NP_ + p0];
    a1 += sv * Ws[n * NP_ + p1];
  }
  float b0 = 0.f, b1 = 0.f;
  for (int q = 0; q < Q_; q++) {
    float cb = conv_b[q];
    b0 += cb * Wf[q * NP_ + p0];
    b1 += cb * Wf[q * NP_ + p1];
  }
  hsb[b * NP_ + p0] = a0 + b0;
  hsb[b * NP_ + p1] = a1 + b1;
}

// ---------------------------------------------------------------------------
// Kernel B: w2[kykx][p] = sum_q conv_w[q][kykx] * Wf[q][p]   (fp32)
// ---------------------------------------------------------------------------
__global__ __launch_bounds__(256) void k_w2(const float* __restrict__ conv_w,
                                            const float* __restrict__ Wf,
                                            float* __restrict__ w2) {
  int kk = blockIdx.x, t = threadIdx.x;
  float a0 = 0.f, a1 = 0.f;
  for (int q = 0; q < Q_; q++) {
    float cw = conv_w[q * KK_ + kk];
    a0 += cw * Wf[q * NP_ + t];
    a1 += cw * Wf[q * NP_ + t + 256];
  }
  w2[kk * NP_ + t]       = a0;
  w2[kk * NP_ + t + 256] = a1;
}

// ---------------------------------------------------------------------------
// Kernel B2: frag-packed Wb (bf16 hi only, R20-verified):
//   Wbp[(ptile*52+ktile)*512 + lane*8 + kidx], lane=(p&31)+((k>>3)&1)*32
// ---------------------------------------------------------------------------
__global__ __launch_bounds__(512) void k_wb(const float* __restrict__ Wa,
                                            const float* __restrict__ w2,
                                            unsigned short* __restrict__ Wbp) {
  const int k = blockIdx.x;          // 0..831
  const int p = threadIdx.x;         // 0..511
  float val = 0.f;
  if (k < KI_)          val = Wa[(size_t)k * NP_ + p];
  else if (k < KPATCH_) val = w2[(size_t)(k - KI_) * NP_ + p];
  const int ptile = p >> 5, ktile = k >> 4;
  const int lane = (p & 31) + (((k >> 3) & 1) << 5);
  const int kidx = k & 7;
  Wbp[((size_t)(ptile * KTILES_ + ktile)) * 512 + lane * 8 + kidx] = f2bf(val);
}

// ---------------------------------------------------------------------------
// Kernel C: fused energy via MFMA (pure bf16 A and B, fp32 accum).
// R24 = R22/R23's math + FINER BLOCKS: 256 thr = 4 waves; wave 32l x 128p
// (4 ptiles, acc[4] = 64 AGPR); block still covers all 512 p (no duplicate
// staging). 4 blocks/CU (vs 2) -> one block's stage/barrier phase overlaps
// three others' MFMA phases. 2-deep e/o B pipe per nt (8 x bf16x8 = 32 VGPR,
// R16-verified parity scheme). Staging = R14's 1x ds_write_b128 form (32 rows).
// ---------------------------------------------------------------------------
__global__ __launch_bounds__(256, 4) void k_energy(const float* __restrict__ i_,
                                                   const float* __restrict__ alpha,
                                                   const unsigned short* __restrict__ Wbp,
                                                   const float* __restrict__ hsb,
                                                   const float* __restrict__ v,
                                                   float* __restrict__ e_out) {
  __shared__ __attribute__((aligned(16))) unsigned char As[2][BM_ * 128]; // 8 KB
  __shared__ float pe[4][BM_];

  const int tid = threadIdx.x, w = tid >> 6, lane = tid & 63;
  const int R0 = blockIdx.x * BM_;
  const int bb = R0 / L_;                      // whole block in one b (32 | L_)
  const int l0 = R0 - bb * L_;

  f32x16 acc[4];
#pragma unroll
  for (int nt = 0; nt < 4; nt++)
#pragma unroll
    for (int r = 0; r < 16; r++) acc[nt][r] = 0.f;

  // --- staging: row sr = tid&31, kq = (tid>>5)*8 (8 k-groups x 32 rows) ---
  const int sr = tid & 31;
  const int kq = (tid >> 5) * 8;               // 0,8,...,56
  const int sl = l0 + sr;
  const size_t ibase = (size_t)bb * ((size_t)C_ * L_) + sl;
  const int ly = sl / W_, lx = sl - ly * W_;

  float xs[8];
  auto stage_load = [&](int ch) {
    const int kb = ch * KC_ + kq;
    if (ch < 10) {                             // all k <= 639: pure-i coalesced
#pragma unroll
      for (int j = 0; j < 8; j++)
        xs[j] = i_[ibase + (size_t)(kb + j) * L_];
    } else {
#pragma unroll
      for (int j = 0; j < 8; j++) {
        int k = kb + j;
        float t = 0.f;
        if (k < KI_) {
          t = i_[ibase + (size_t)k * L_];
        } else if (k < KPATCH_) {
          int kkp = k - KI_;
          int ky = kkp / 11, kx = kkp - ky * 11;
          int yy = ly + ky - 5, xx = lx + kx - 5;
          if (yy >= 0 && yy < H_ && xx >= 0 && xx < W_)
            t = alpha[(size_t)bb * L_ + yy * W_ + xx];
        }
        xs[j] = t;
      }
    }
  };
  // convert + one swizzled ds_write_b128; slot16 = (kq>>3) ^ (sr&7)
  auto stage_write = [&](int buf) {
    bf16x8 hv;
#pragma unroll
    for (int j = 0; j < 8; j++) hv[j] = f2bf_fast(xs[j]);
    const int byte = sr * 128 + (((kq >> 3) ^ (sr & 7)) << 4);
    *(bf16x8*)(&As[buf][byte]) = hv;
  };

  // prologue (R13 order)
  stage_load(0);
  stage_write(0);
  __syncthreads();

  // compute-side indices (R13-verified read path)
  const int col = lane & 31, half = lane >> 5;
  const int abase = col * 128;                 // A row = col (32-row tile)
  const int aswz = col & 7;
  const unsigned short* wbp_[4];
#pragma unroll
  for (int nt = 0; nt < 4; nt++)
    wbp_[nt] = Wbp + ((size_t)(w * 4 + nt) * KTILES_) * 512 + lane * 8;

  // B-pipeline prologue (2-deep e/o, R16-verified): e-set g=0, o-set g=1
  bf16x8 eb[4], ob[4];
#pragma unroll
  for (int nt = 0; nt < 4; nt++) {
    eb[nt] = *(const bf16x8*)(wbp_[nt]);
    ob[nt] = *(const bf16x8*)(wbp_[nt] + 512);
  }

  int buf = 0;
  for (int ch = 0; ch < NCH_; ch++) {
    if (ch + 1 < NCH_) stage_load(ch + 1);     // next-chunk A loads in flight

#pragma unroll
    for (int ks = 0; ks < 4; ks++) {
      const int g = ch * 4 + ks;
      const int aoff = abase + (((ks * 2 + half) ^ aswz) << 4);
      bf16x8 ah = *(const bf16x8*)(&As[buf][aoff]);
      if ((ks & 1) == 0) {                     // even g: consume e-set
        __builtin_amdgcn_s_setprio(1);
        acc[0] = MFMA32(ah, eb[0], acc[0]);
        acc[1] = MFMA32(ah, eb[1], acc[1]);
        acc[2] = MFMA32(ah, eb[2], acc[2]);
        acc[3] = MFMA32(ah, eb[3], acc[3]);
        __builtin_amdgcn_s_setprio(0);
        if (g + 2 < KTILES_) {                 // refill e-set with g+2
          const size_t o = (size_t)(g + 2) * 512;
#pragma unroll
          for (int nt = 0; nt < 4; nt++)
            eb[nt] = *(const bf16x8*)(wbp_[nt] + o);
        }
      } else {                                 // odd g: consume o-set
        __builtin_amdgcn_s_setprio(1);
        acc[0] = MFMA32(ah, ob[0], acc[0]);
        acc[1] = MFMA32(ah, ob[1], acc[1]);
        acc[2] = MFMA32(ah, ob[2], acc[2]);
        acc[3] = MFMA32(ah, ob[3], acc[3]);
        __builtin_amdgcn_s_setprio(0);
        if (g + 2 < KTILES_) {                 // refill o-set with g+2
          const size_t o = (size_t)(g + 2) * 512;
#pragma unroll
          for (int nt = 0; nt < 4; nt++)
            ob[nt] = *(const bf16x8*)(wbp_[nt] + o);
        }
      }
    }

    if (ch + 1 < NCH_) {
      stage_write(buf ^ 1);                    // convert + LDS write after MFMA
      __syncthreads();
      buf ^= 1;
    }
  }

  // epilogue: pre = acc + hsb[bb][p]; e partial over this wave's 128 p
  float hv[4], vv[4];
#pragma unroll
  for (int nt = 0; nt < 4; nt++) {
    const int p = w * 128 + nt * 32 + col;
    hv[nt] = hsb[bb * NP_ + p];
    vv[nt] = v[p];
  }
#pragma unroll
  for (int r = 0; r < 16; r++) {
    float val = 0.f;
#pragma unroll
    for (int nt = 0; nt < 4; nt++)
      val += vv[nt] * tanhf(acc[nt][r] + hv[nt]);
    val += __shfl_xor(val, 16);
    val += __shfl_xor(val, 8);
    val += __shfl_xor(val, 4);
    val += __shfl_xor(val, 2);
    val += __shfl_xor(val, 1);
    if (col == 0) {
      int row = (r & 3) + 8 * (r >> 2) + 4 * half;
      pe[w][row] = val;
    }
  }
  __syncthreads();
  if (tid < BM_) {
    float s = pe[0][tid] + pe[1][tid] + pe[2][tid] + pe[3][tid];
    e_out[(size_t)(R0 + tid)] = s;
  }
}

// ---------------------------------------------------------------------------
// Kernel D: softmax over L per batch (single e, R13 form).
// ---------------------------------------------------------------------------
__global__ __launch_bounds__(256) void k_softmax(const float* __restrict__ e,
                                                 float* __restrict__ w) {
  __shared__ float sh[L_];
  __shared__ float red[4];
  const int b = blockIdx.x, tid = threadIdx.x;
  const int lane = tid & 63, wv = tid >> 6;

  float m = -1e30f;
  for (int idx = tid; idx < L_; idx += 256) {
    float t = e[(size_t)b * L_ + idx];
    sh[idx] = t;
    m = fmaxf(m, t);
  }
  m = fmaxf(m, __shfl_down(m, 32));
  m = fmaxf(m, __shfl_down(m, 16));
  m = fmaxf(m, __shfl_down(m, 8));
  m = fmaxf(m, __shfl_down(m, 4));
  m = fmaxf(m, __shfl_down(m, 2));
  m = fmaxf(m, __shfl_down(m, 1));
  if (lane == 0) red[wv] = m;
  __syncthreads();
  m = fmaxf(fmaxf(red[0], red[1]), fmaxf(red[2], red[3]));
  __syncthreads();

  float s = 0.f;
  for (int idx = tid; idx < L_; idx += 256) {
    float t = expf(sh[idx] - m);
    sh[idx] = t;
    s += t;
  }
  s += __shfl_down(s, 32);
  s += __shfl_down(s, 16);
  s += __shfl_down(s, 8);
  s += __shfl_down(s, 4);
  s += __shfl_down(s, 2);
  s += __shfl_down(s, 1);
  if (lane == 0) red[wv] = s;
  __syncthreads();
  float total = red[0] + red[1] + red[2] + red[3];
  float inv = 1.f / total;
  for (int idx = tid; idx < L_; idx += 256)
    w[(size_t)b * L_ + idx] = sh[idx] * inv;
}

// ---------------------------------------------------------------------------
// Kernel E: context c_At[b][c] = sum_l w[b][l] * i[b][c][l]  (memory-bound)
// ---------------------------------------------------------------------------
__global__ __launch_bounds__(256) void k_context(const float* __restrict__ i_,
                                                 const float* __restrict__ w,
                                                 float* __restrict__ out) {
  __shared__ float red[4];
  const int b = blockIdx.y, c = blockIdx.x, tid = threadIdx.x;
  const int lane = tid & 63, wv = tid >> 6;
  const float4* row = (const float4*)(i_ + ((size_t)b * C_ + c) * L_);
  const float4* wr  = (const float4*)(w + (size_t)b * L_);
  float s = 0.f;
  for (int idx = tid; idx < L_ / 4; idx += 256) {
    float4 a = row[idx];
    float4 ww = wr[idx];
    s += a.x * ww.x + a.y * ww.y + a.z * ww.z + a.w * ww.w;
  }
  s += __shfl_down(s, 32);
  s += __shfl_down(s, 16);
  s += __shfl_down(s, 8);
  s += __shfl_down(s, 4);
  s += __shfl_down(s, 2);
  s += __shfl_down(s, 1);
  if (lane == 0) red[wv] = s;
  __syncthreads();
  if (tid == 0) out[(size_t)b * C_ + c] = red[0] + red[1] + red[2] + red[3];
}

// ---------------------------------------------------------------------------
extern "C" void kernel_launch(void* const* d_in, const int* in_sizes, int n_in,
                              void* d_out, int out_size, void* d_ws, size_t ws_size,
                              hipStream_t stream) {
  const float* i_      = (const float*)d_in[0];
  const float* hat_s_t = (const float*)d_in[1];
  const float* alpha   = (const float*)d_in[2];
  const float* conv_w  = (const float*)d_in[3];
  const float* conv_b  = (const float*)d_in[4];
  const float* Wa      = (const float*)d_in[5];
  const float* Wf      = (const float*)d_in[6];
  const float* Ws      = (const float*)d_in[7];
  const float* v       = (const float*)d_in[8];
  float* out = (float*)d_out;

  float* ws   = (float*)d_ws;
  float* hsb  = ws;                               // 32*512    f
  float* w2   = hsb + B_ * NP_;                   // 121*512   f
  float* e    = w2 + KK_ * NP_;                   // 32*3136   f
  float* anew = e + B_ * L_;                      // 32*3136   f
  unsigned short* Wbp = (unsigned short*)(anew + B_ * L_);  // 16*52*512 u16 = 832 KB
  // total ~2.1 MB workspace

  k_hsb<<<dim3(B_), dim3(256), 0, stream>>>(hat_s_t, Ws, conv_b, Wf, hsb);
  k_w2<<<dim3(KK_), dim3(256), 0, stream>>>(conv_w, Wf, w2);
  k_wb<<<dim3(KT_), dim3(512), 0, stream>>>(Wa, w2, Wbp);
  k_energy<<<dim3((B_ * L_) / BM_), dim3(256), 0, stream>>>(i_, alpha, Wbp, hsb, v, e);
  k_softmax<<<dim3(B_), dim3(256), 0, stream>>>(e, anew);
  k_context<<<dim3(C_, B_), dim3(256), 0, stream>>>(i_, anew, out);
}

// Round 25
// 271.209 us; speedup vs baseline: 2.1569x; 2.1569x over previous
//
#include <hip/hip_runtime.h>
#include <hip/hip_bf16.h>
#include <math.h>

#define B_   32
#define C_   684
#define H_   28
#define W_   112
#define L_   3136      // H_*W_
#define Q_   256
#define NP_  512
#define N_   256
#define K_   11
#define KK_  121       // K_*K_
#define KI_  684       // K rows from i
#define KPATCH_ 805    // 684 + 121 (im2col of alpha)
#define KT_  832       // padded K = 13*64
#define KTILES_ 52     // KT_/16
#define BM_  64        // l rows per block (64 | L_, so block lies in one b)
#define KC_  64        // K chunk staged in LDS
#define NCH_ 13        // KT_/KC_

typedef short bf16x8  __attribute__((ext_vector_type(8)));
typedef float f32x16  __attribute__((ext_vector_type(16)));

#define MFMA32(a, b, c) __builtin_amdgcn_mfma_f32_32x32x16_bf16((a), (b), (c), 0, 0, 0)

// fp32 -> bf16 round-to-nearest-even (bit trick)
__device__ __forceinline__ unsigned short f2bf(float x) {
  unsigned u = __float_as_uint(x);
  u += 0x7FFF + ((u >> 16) & 1);
  return (unsigned short)(u >> 16);
}
// cast-path conversion (same RNE; compiler can emit v_cvt_pk_bf16_f32)
__device__ __forceinline__ short f2bf_fast(float x) {
  __hip_bfloat16 h = __float2bfloat16(x);
  return *reinterpret_cast<short*>(&h);
}

// ---------------------------------------------------------------------------
// Kernel A: hsb[b][p] = sum_n s[b][n]*Ws[n][p] + sum_q conv_b[q]*Wf[q][p]
// ---------------------------------------------------------------------------
__global__ __launch_bounds__(256) void k_hsb(const float* __restrict__ s,
                                             const float* __restrict__ Ws,
                                             const float* __restrict__ conv_b,
                                             const float* __restrict__ Wf,
                                             float* __restrict__ hsb) {
  int b = blockIdx.x, t = threadIdx.x;
  int p0 = t, p1 = t + 256;
  float a0 = 0.f, a1 = 0.f;
  for (int n = 0; n < N_; n++) {
    float sv = s[b * N_ + n];
    a0 += sv * Ws[n * NP_ + p0];
    a1 += sv * Ws[n * NP_ + p1];
  }
  float b0 = 0.f, b1 = 0.f;
  for (int q = 0; q < Q_; q++) {
    float cb = conv_b[q];
    b0 += cb * Wf[q * NP_ + p0];
    b1 += cb * Wf[q * NP_ + p1];
  }
  hsb[b * NP_ + p0] = a0 + b0;
  hsb[b * NP_ + p1] = a1 + b1;
}

// ---------------------------------------------------------------------------
// Kernel B: w2[kykx][p] = sum_q conv_w[q][kykx] * Wf[q][p]   (fp32)
// ---------------------------------------------------------------------------
__global__ __launch_bounds__(256) void k_w2(const float* __restrict__ conv_w,
                                            const float* __restrict__ Wf,
                                            float* __restrict__ w2) {
  int kk = blockIdx.x, t = threadIdx.x;
  float a0 = 0.f, a1 = 0.f;
  for (int q = 0; q < Q_; q++) {
    float cw = conv_w[q * KK_ + kk];
    a0 += cw * Wf[q * NP_ + t];
    a1 += cw * Wf[q * NP_ + t + 256];
  }
  w2[kk * NP_ + t]       = a0;
  w2[kk * NP_ + t + 256] = a1;
}

// ---------------------------------------------------------------------------
// Kernel B2: frag-packed Wb (bf16 hi only, R20-verified):
//   Wbp[(ptile*52+ktile)*512 + lane*8 + kidx], lane=(p&31)+((k>>3)&1)*32
// ---------------------------------------------------------------------------
__global__ __launch_bounds__(512) void k_wb(const float* __restrict__ Wa,
                                            const float* __restrict__ w2,
                                            unsigned short* __restrict__ Wbp) {
  const int k = blockIdx.x;          // 0..831
  const int p = threadIdx.x;         // 0..511
  float val = 0.f;
  if (k < KI_)          val = Wa[(size_t)k * NP_ + p];
  else if (k < KPATCH_) val = w2[(size_t)(k - KI_) * NP_ + p];
  const int ptile = p >> 5, ktile = k >> 4;
  const int lane = (p & 31) + (((k >> 3) & 1) << 5);
  const int kidx = k & 7;
  Wbp[((size_t)(ptile * KTILES_ + ktile)) * 512 + lane * 8 + kidx] = f2bf(val);
}

// ---------------------------------------------------------------------------
// Kernel C: fused energy via MFMA (pure bf16 A and B, fp32 accum).
// R25 = R14 geometry (wave 64l x 64p, acc[2][2]) which NOW fits the register
// bracket because B is hi-only (R20): 2-deep e/o pipe for 2 ptiles = 4 x
// bf16x8 = 16 VGPR; 64 AGPR + ~40 VGPR ~ 105 total <= 128, no spill expected.
// Per ks: 2 A ds_reads + 2 B loads -> 4 MFMA. Blocks halve vs R23 (1568):
// per-element barriers halve, B L2 traffic halves. All pieces verified:
// R14 staging/dual-row reads, R16 parity pipeline, R13 schedule, R14 epilogue.
// ---------------------------------------------------------------------------
__global__ __launch_bounds__(512, 4) void k_energy(const float* __restrict__ i_,
                                                   const float* __restrict__ alpha,
                                                   const unsigned short* __restrict__ Wbp,
                                                   const float* __restrict__ hsb,
                                                   const float* __restrict__ v,
                                                   float* __restrict__ e_out) {
  __shared__ __attribute__((aligned(16))) unsigned char As[2][BM_ * 128]; // 16 KB
  __shared__ float pe[8][BM_];

  const int tid = threadIdx.x, w = tid >> 6, lane = tid & 63;
  const int R0 = blockIdx.x * BM_;
  const int bb = R0 / L_;                      // whole block in one b (64 | L_)
  const int l0 = R0 - bb * L_;

  f32x16 acc[2][2];                            // [mt][nt]
#pragma unroll
  for (int mt = 0; mt < 2; mt++)
#pragma unroll
    for (int nt = 0; nt < 2; nt++)
#pragma unroll
      for (int r = 0; r < 16; r++) acc[mt][nt][r] = 0.f;

  // --- staging (R14-verified): row sr = tid&63, kq = (tid>>6)*8 ---
  const int sr = tid & 63;
  const int kq = (tid >> 6) * 8;               // 0,8,...,56
  const int sl = l0 + sr;
  const size_t ibase = (size_t)bb * ((size_t)C_ * L_) + sl;
  const int ly = sl / W_, lx = sl - ly * W_;

  float xs[8];
  auto stage_load = [&](int ch) {
    const int kb = ch * KC_ + kq;
    if (ch < 10) {                             // all k <= 639: pure-i coalesced
#pragma unroll
      for (int j = 0; j < 8; j++)
        xs[j] = i_[ibase + (size_t)(kb + j) * L_];
    } else {
#pragma unroll
      for (int j = 0; j < 8; j++) {
        int k = kb + j;
        float t = 0.f;
        if (k < KI_) {
          t = i_[ibase + (size_t)k * L_];
        } else if (k < KPATCH_) {
          int kkp = k - KI_;
          int ky = kkp / 11, kx = kkp - ky * 11;
          int yy = ly + ky - 5, xx = lx + kx - 5;
          if (yy >= 0 && yy < H_ && xx >= 0 && xx < W_)
            t = alpha[(size_t)bb * L_ + yy * W_ + xx];
        }
        xs[j] = t;
      }
    }
  };
  // convert + one swizzled ds_write_b128; slot16 = (kq>>3) ^ (sr&7)
  auto stage_write = [&](int buf) {
    bf16x8 hv;
#pragma unroll
    for (int j = 0; j < 8; j++) hv[j] = f2bf_fast(xs[j]);
    const int byte = sr * 128 + (((kq >> 3) ^ (sr & 7)) << 4);
    *(bf16x8*)(&As[buf][byte]) = hv;
  };

  // prologue (R13 order)
  stage_load(0);
  stage_write(0);
  __syncthreads();

  // compute-side indices (R14-verified dual-row read; same swz key for +32)
  const int col = lane & 31, half = lane >> 5;
  const int abase0 = col * 128;
  const int abase1 = (col + 32) * 128;
  const int aswz = col & 7;
  const unsigned short* wb0 = Wbp + ((size_t)(w * 2 + 0) * KTILES_) * 512 + lane * 8;
  const unsigned short* wb1 = Wbp + ((size_t)(w * 2 + 1) * KTILES_) * 512 + lane * 8;

  // B-pipeline prologue (2-deep e/o, hi-only): e-set g=0, o-set g=1
  bf16x8 eb0 = *(const bf16x8*)(wb0);
  bf16x8 eb1 = *(const bf16x8*)(wb1);
  bf16x8 ob0 = *(const bf16x8*)(wb0 + 512);
  bf16x8 ob1 = *(const bf16x8*)(wb1 + 512);

  int buf = 0;
  for (int ch = 0; ch < NCH_; ch++) {
    if (ch + 1 < NCH_) stage_load(ch + 1);     // next-chunk A loads in flight

#pragma unroll
    for (int ks = 0; ks < 4; ks++) {
      const int g = ch * 4 + ks;
      const int soff = (((ks * 2 + half) ^ aswz) << 4);
      bf16x8 ah0 = *(const bf16x8*)(&As[buf][abase0 + soff]);
      bf16x8 ah1 = *(const bf16x8*)(&As[buf][abase1 + soff]);
      if ((ks & 1) == 0) {                     // even g: consume e-set
        __builtin_amdgcn_s_setprio(1);
        acc[0][0] = MFMA32(ah0, eb0, acc[0][0]);
        acc[0][1] = MFMA32(ah0, eb1, acc[0][1]);
        acc[1][0] = MFMA32(ah1, eb0, acc[1][0]);
        acc[1][1] = MFMA32(ah1, eb1, acc[1][1]);
        __builtin_amdgcn_s_setprio(0);
        if (g + 2 < KTILES_) {                 // refill e-set with g+2
          const size_t o = (size_t)(g + 2) * 512;
          eb0 = *(const bf16x8*)(wb0 + o);
          eb1 = *(const bf16x8*)(wb1 + o);
        }
      } else {                                 // odd g: consume o-set
        __builtin_amdgcn_s_setprio(1);
        acc[0][0] = MFMA32(ah0, ob0, acc[0][0]);
        acc[0][1] = MFMA32(ah0, ob1, acc[0][1]);
        acc[1][0] = MFMA32(ah1, ob0, acc[1][0]);
        acc[1][1] = MFMA32(ah1, ob1, acc[1][1]);
        __builtin_amdgcn_s_setprio(0);
        if (g + 2 < KTILES_) {                 // refill o-set with g+2
          const size_t o = (size_t)(g + 2) * 512;
          ob0 = *(const bf16x8*)(wb0 + o);
          ob1 = *(const bf16x8*)(wb1 + o);
        }
      }
    }

    if (ch + 1 < NCH_) {
      stage_write(buf ^ 1);                    // convert + LDS write after MFMA
      __syncthreads();
      buf ^= 1;
    }
  }

  // epilogue (R14-verified): pre = acc + hsb[bb][p]; e over this wave's 64 p
  const int p0 = w * 64 + col, p1 = p0 + 32;
  const float h0 = hsb[bb * NP_ + p0], h1 = hsb[bb * NP_ + p1];
  const float v0 = v[p0], v1 = v[p1];
#pragma unroll
  for (int mt = 0; mt < 2; mt++) {
#pragma unroll
    for (int r = 0; r < 16; r++) {
      float val = v0 * tanhf(acc[mt][0][r] + h0) + v1 * tanhf(acc[mt][1][r] + h1);
      val += __shfl_xor(val, 16);
      val += __shfl_xor(val, 8);
      val += __shfl_xor(val, 4);
      val += __shfl_xor(val, 2);
      val += __shfl_xor(val, 1);
      if (col == 0) {
        int row = mt * 32 + (r & 3) + 8 * (r >> 2) + 4 * half;
        pe[w][row] = val;
      }
    }
  }
  __syncthreads();
  if (tid < BM_) {
    float s = 0.f;
#pragma unroll
    for (int ww = 0; ww < 8; ww++) s += pe[ww][tid];
    e_out[(size_t)(R0 + tid)] = s;
  }
}

// ---------------------------------------------------------------------------
// Kernel D: softmax over L per batch (single e, R13 form).
// ---------------------------------------------------------------------------
__global__ __launch_bounds__(256) void k_softmax(const float* __restrict__ e,
                                                 float* __restrict__ w) {
  __shared__ float sh[L_];
  __shared__ float red[4];
  const int b = blockIdx.x, tid = threadIdx.x;
  const int lane = tid & 63, wv = tid >> 6;

  float m = -1e30f;
  for (int idx = tid; idx < L_; idx += 256) {
    float t = e[(size_t)b * L_ + idx];
    sh[idx] = t;
    m = fmaxf(m, t);
  }
  m = fmaxf(m, __shfl_down(m, 32));
  m = fmaxf(m, __shfl_down(m, 16));
  m = fmaxf(m, __shfl_down(m, 8));
  m = fmaxf(m, __shfl_down(m, 4));
  m = fmaxf(m, __shfl_down(m, 2));
  m = fmaxf(m, __shfl_down(m, 1));
  if (lane == 0) red[wv] = m;
  __syncthreads();
  m = fmaxf(fmaxf(red[0], red[1]), fmaxf(red[2], red[3]));
  __syncthreads();

  float s = 0.f;
  for (int idx = tid; idx < L_; idx += 256) {
    float t = expf(sh[idx] - m);
    sh[idx] = t;
    s += t;
  }
  s += __shfl_down(s, 32);
  s += __shfl_down(s, 16);
  s += __shfl_down(s, 8);
  s += __shfl_down(s, 4);
  s += __shfl_down(s, 2);
  s += __shfl_down(s, 1);
  if (lane == 0) red[wv] = s;
  __syncthreads();
  float total = red[0] + red[1] + red[2] + red[3];
  float inv = 1.f / total;
  for (int idx = tid; idx < L_; idx += 256)
    w[(size_t)b * L_ + idx] = sh[idx] * inv;
}

// ---------------------------------------------------------------------------
// Kernel E: context c_At[b][c] = sum_l w[b][l] * i[b][c][l]  (memory-bound)
// ---------------------------------------------------------------------------
__global__ __launch_bounds__(256) void k_context(const float* __restrict__ i_,
                                                 const float* __restrict__ w,
                                                 float* __restrict__ out) {
  __shared__ float red[4];
  const int b = blockIdx.y, c = blockIdx.x, tid = threadIdx.x;
  const int lane = tid & 63, wv = tid >> 6;
  const float4* row = (const float4*)(i_ + ((size_t)b * C_ + c) * L_);
  const float4* wr  = (const float4*)(w + (size_t)b * L_);
  float s = 0.f;
  for (int idx = tid; idx < L_ / 4; idx += 256) {
    float4 a = row[idx];
    float4 ww = wr[idx];
    s += a.x * ww.x + a.y * ww.y + a.z * ww.z + a.w * ww.w;
  }
  s += __shfl_down(s, 32);
  s += __shfl_down(s, 16);
  s += __shfl_down(s, 8);
  s += __shfl_down(s, 4);
  s += __shfl_down(s, 2);
  s += __shfl_down(s, 1);
  if (lane == 0) red[wv] = s;
  __syncthreads();
  if (tid == 0) out[(size_t)b * C_ + c] = red[0] + red[1] + red[2] + red[3];
}

// ---------------------------------------------------------------------------
extern "C" void kernel_launch(void* const* d_in, const int* in_sizes, int n_in,
                              void* d_out, int out_size, void* d_ws, size_t ws_size,
                              hipStream_t stream) {
  const float* i_      = (const float*)d_in[0];
  const float* hat_s_t = (const float*)d_in[1];
  const float* alpha   = (const float*)d_in[2];
  const float* conv_w  = (const float*)d_in[3];
  const float* conv_b  = (const float*)d_in[4];
  const float* Wa      = (const float*)d_in[5];
  const float* Wf      = (const float*)d_in[6];
  const float* Ws      = (const float*)d_in[7];
  const float* v       = (const float*)d_in[8];
  float* out = (float*)d_out;

  float* ws   = (float*)d_ws;
  float* hsb  = ws;                               // 32*512    f
  float* w2   = hsb + B_ * NP_;                   // 121*512   f
  float* e    = w2 + KK_ * NP_;                   // 32*3136   f
  float* anew = e + B_ * L_;                      // 32*3136   f
  unsigned short* Wbp = (unsigned short*)(anew + B_ * L_);  // 16*52*512 u16 = 832 KB
  // total ~2.1 MB workspace

  k_hsb<<<dim3(B_), dim3(256), 0, stream>>>(hat_s_t, Ws, conv_b, Wf, hsb);
  k_w2<<<dim3(KK_), dim3(256), 0, stream>>>(conv_w, Wf, w2);
  k_wb<<<dim3(KT_), dim3(512), 0, stream>>>(Wa, w2, Wbp);
  k_energy<<<dim3((B_ * L_) / BM_), dim3(512), 0, stream>>>(i_, alpha, Wbp, hsb, v, e);
  k_softmax<<<dim3(B_), dim3(256), 0, stream>>>(e, anew);
  k_context<<<dim3(C_, B_), dim3(256), 0, stream>>>(i_, anew, out);
}

// Round 26
// 255.452 us; speedup vs baseline: 2.2899x; 1.0617x over previous
//
#include <hip/hip_runtime.h>
#include <hip/hip_bf16.h>
#include <math.h>

#define B_   32
#define C_   684
#define H_   28
#define W_   112
#define L_   3136      // H_*W_
#define Q_   256
#define NP_  512
#define N_   256
#define K_   11
#define KK_  121       // K_*K_
#define KI_  684       // K rows from i
#define KPATCH_ 805    // 684 + 121 (im2col of alpha)
#define KT_  832       // padded K = 13*64
#define KTILES_ 52     // KT_/16
#define BM_  64        // l rows per block (64 | L_, so block lies in one b)
#define KC_  64        // K chunk staged in LDS
#define NCH_ 13        // KT_/KC_

typedef short bf16x8  __attribute__((ext_vector_type(8)));
typedef float f32x16  __attribute__((ext_vector_type(16)));

#define MFMA32(a, b, c) __builtin_amdgcn_mfma_f32_32x32x16_bf16((a), (b), (c), 0, 0, 0)

// fp32 -> bf16 round-to-nearest-even (bit trick)
__device__ __forceinline__ unsigned short f2bf(float x) {
  unsigned u = __float_as_uint(x);
  u += 0x7FFF + ((u >> 16) & 1);
  return (unsigned short)(u >> 16);
}
// cast-path conversion (same RNE; compiler can emit v_cvt_pk_bf16_f32)
__device__ __forceinline__ short f2bf_fast(float x) {
  __hip_bfloat16 h = __float2bfloat16(x);
  return *reinterpret_cast<short*>(&h);
}
// fast tanh via hardware exp2: (e-1)/(e+1), e = 2^(2*log2e*x); |x| clamped
// to 15 (pre ~ N(0,2), never binds). Rel err ~2e-7 << bf16 floor.
__device__ __forceinline__ float fast_tanh(float x) {
  x = fminf(15.f, fmaxf(-15.f, x));
  float e = __builtin_amdgcn_exp2f(x * 2.885390082f);  // 2*log2(e)
  return (e - 1.f) / (e + 1.f);
}

// ---------------------------------------------------------------------------
// Kernel A: hsb[b][p] = sum_n s[b][n]*Ws[n][p] + sum_q conv_b[q]*Wf[q][p]
// ---------------------------------------------------------------------------
__global__ __launch_bounds__(256) void k_hsb(const float* __restrict__ s,
                                             const float* __restrict__ Ws,
                                             const float* __restrict__ conv_b,
                                             const float* __restrict__ Wf,
                                             float* __restrict__ hsb) {
  int b = blockIdx.x, t = threadIdx.x;
  int p0 = t, p1 = t + 256;
  float a0 = 0.f, a1 = 0.f;
  for (int n = 0; n < N_; n++) {
    float sv = s[b * N_ + n];
    a0 += sv * Ws[n * NP_ + p0];
    a1 += sv * Ws[n * NP_ + p1];
  }
  float b0 = 0.f, b1 = 0.f;
  for (int q = 0; q < Q_; q++) {
    float cb = conv_b[q];
    b0 += cb * Wf[q * NP_ + p0];
    b1 += cb * Wf[q * NP_ + p1];
  }
  hsb[b * NP_ + p0] = a0 + b0;
  hsb[b * NP_ + p1] = a1 + b1;
}

// ---------------------------------------------------------------------------
// Kernel B: w2[kykx][p] = sum_q conv_w[q][kykx] * Wf[q][p]   (fp32)
// ---------------------------------------------------------------------------
__global__ __launch_bounds__(256) void k_w2(const float* __restrict__ conv_w,
                                            const float* __restrict__ Wf,
                                            float* __restrict__ w2) {
  int kk = blockIdx.x, t = threadIdx.x;
  float a0 = 0.f, a1 = 0.f;
  for (int q = 0; q < Q_; q++) {
    float cw = conv_w[q * KK_ + kk];
    a0 += cw * Wf[q * NP_ + t];
    a1 += cw * Wf[q * NP_ + t + 256];
  }
  w2[kk * NP_ + t]       = a0;
  w2[kk * NP_ + t + 256] = a1;
}

// ---------------------------------------------------------------------------
// Kernel B2: frag-packed Wb (bf16 hi only, R20-verified):
//   Wbp[(ptile*52+ktile)*512 + lane*8 + kidx], lane=(p&31)+((k>>3)&1)*32
// ---------------------------------------------------------------------------
__global__ __launch_bounds__(512) void k_wb(const float* __restrict__ Wa,
                                            const float* __restrict__ w2,
                                            unsigned short* __restrict__ Wbp) {
  const int k = blockIdx.x;          // 0..831
  const int p = threadIdx.x;         // 0..511
  float val = 0.f;
  if (k < KI_)          val = Wa[(size_t)k * NP_ + p];
  else if (k < KPATCH_) val = w2[(size_t)(k - KI_) * NP_ + p];
  const int ptile = p >> 5, ktile = k >> 4;
  const int lane = (p & 31) + (((k >> 3) & 1) << 5);
  const int kidx = k & 7;
  Wbp[((size_t)(ptile * KTILES_ + ktile)) * 512 + lane * 8 + kidx] = f2bf(val);
}

// ---------------------------------------------------------------------------
// Kernel C: fused energy via MFMA (pure bf16 A and B, fp32 accum).
// R26 = R25 (verified, 198 us) with ONE register-only change: library tanhf
// replaced by fast_tanh (hardware v_exp_f32, ~6 ops vs ~20) in the epilogue
// (64 calls/thread ~ 20% of VALUBusy). Everything else verbatim.
// ---------------------------------------------------------------------------
__global__ __launch_bounds__(512, 4) void k_energy(const float* __restrict__ i_,
                                                   const float* __restrict__ alpha,
                                                   const unsigned short* __restrict__ Wbp,
                                                   const float* __restrict__ hsb,
                                                   const float* __restrict__ v,
                                                   float* __restrict__ e_out) {
  __shared__ __attribute__((aligned(16))) unsigned char As[2][BM_ * 128]; // 16 KB
  __shared__ float pe[8][BM_];

  const int tid = threadIdx.x, w = tid >> 6, lane = tid & 63;
  const int R0 = blockIdx.x * BM_;
  const int bb = R0 / L_;                      // whole block in one b (64 | L_)
  const int l0 = R0 - bb * L_;

  f32x16 acc[2][2];                            // [mt][nt]
#pragma unroll
  for (int mt = 0; mt < 2; mt++)
#pragma unroll
    for (int nt = 0; nt < 2; nt++)
#pragma unroll
      for (int r = 0; r < 16; r++) acc[mt][nt][r] = 0.f;

  // --- staging (R14-verified): row sr = tid&63, kq = (tid>>6)*8 ---
  const int sr = tid & 63;
  const int kq = (tid >> 6) * 8;               // 0,8,...,56
  const int sl = l0 + sr;
  const size_t ibase = (size_t)bb * ((size_t)C_ * L_) + sl;
  const int ly = sl / W_, lx = sl - ly * W_;

  float xs[8];
  auto stage_load = [&](int ch) {
    const int kb = ch * KC_ + kq;
    if (ch < 10) {                             // all k <= 639: pure-i coalesced
#pragma unroll
      for (int j = 0; j < 8; j++)
        xs[j] = i_[ibase + (size_t)(kb + j) * L_];
    } else {
#pragma unroll
      for (int j = 0; j < 8; j++) {
        int k = kb + j;
        float t = 0.f;
        if (k < KI_) {
          t = i_[ibase + (size_t)k * L_];
        } else if (k < KPATCH_) {
          int kkp = k - KI_;
          int ky = kkp / 11, kx = kkp - ky * 11;
          int yy = ly + ky - 5, xx = lx + kx - 5;
          if (yy >= 0 && yy < H_ && xx >= 0 && xx < W_)
            t = alpha[(size_t)bb * L_ + yy * W_ + xx];
        }
        xs[j] = t;
      }
    }
  };
  // convert + one swizzled ds_write_b128; slot16 = (kq>>3) ^ (sr&7)
  auto stage_write = [&](int buf) {
    bf16x8 hv;
#pragma unroll
    for (int j = 0; j < 8; j++) hv[j] = f2bf_fast(xs[j]);
    const int byte = sr * 128 + (((kq >> 3) ^ (sr & 7)) << 4);
    *(bf16x8*)(&As[buf][byte]) = hv;
  };

  // prologue (R13 order)
  stage_load(0);
  stage_write(0);
  __syncthreads();

  // compute-side indices (R14-verified dual-row read; same swz key for +32)
  const int col = lane & 31, half = lane >> 5;
  const int abase0 = col * 128;
  const int abase1 = (col + 32) * 128;
  const int aswz = col & 7;
  const unsigned short* wb0 = Wbp + ((size_t)(w * 2 + 0) * KTILES_) * 512 + lane * 8;
  const unsigned short* wb1 = Wbp + ((size_t)(w * 2 + 1) * KTILES_) * 512 + lane * 8;

  // B-pipeline prologue (2-deep e/o, hi-only): e-set g=0, o-set g=1
  bf16x8 eb0 = *(const bf16x8*)(wb0);
  bf16x8 eb1 = *(const bf16x8*)(wb1);
  bf16x8 ob0 = *(const bf16x8*)(wb0 + 512);
  bf16x8 ob1 = *(const bf16x8*)(wb1 + 512);

  int buf = 0;
  for (int ch = 0; ch < NCH_; ch++) {
    if (ch + 1 < NCH_) stage_load(ch + 1);     // next-chunk A loads in flight

#pragma unroll
    for (int ks = 0; ks < 4; ks++) {
      const int g = ch * 4 + ks;
      const int soff = (((ks * 2 + half) ^ aswz) << 4);
      bf16x8 ah0 = *(const bf16x8*)(&As[buf][abase0 + soff]);
      bf16x8 ah1 = *(const bf16x8*)(&As[buf][abase1 + soff]);
      if ((ks & 1) == 0) {                     // even g: consume e-set
        __builtin_amdgcn_s_setprio(1);
        acc[0][0] = MFMA32(ah0, eb0, acc[0][0]);
        acc[0][1] = MFMA32(ah0, eb1, acc[0][1]);
        acc[1][0] = MFMA32(ah1, eb0, acc[1][0]);
        acc[1][1] = MFMA32(ah1, eb1, acc[1][1]);
        __builtin_amdgcn_s_setprio(0);
        if (g + 2 < KTILES_) {                 // refill e-set with g+2
          const size_t o = (size_t)(g + 2) * 512;
          eb0 = *(const bf16x8*)(wb0 + o);
          eb1 = *(const bf16x8*)(wb1 + o);
        }
      } else {                                 // odd g: consume o-set
        __builtin_amdgcn_s_setprio(1);
        acc[0][0] = MFMA32(ah0, ob0, acc[0][0]);
        acc[0][1] = MFMA32(ah0, ob1, acc[0][1]);
        acc[1][0] = MFMA32(ah1, ob0, acc[1][0]);
        acc[1][1] = MFMA32(ah1, ob1, acc[1][1]);
        __builtin_amdgcn_s_setprio(0);
        if (g + 2 < KTILES_) {                 // refill o-set with g+2
          const size_t o = (size_t)(g + 2) * 512;
          ob0 = *(const bf16x8*)(wb0 + o);
          ob1 = *(const bf16x8*)(wb1 + o);
        }
      }
    }

    if (ch + 1 < NCH_) {
      stage_write(buf ^ 1);                    // convert + LDS write after MFMA
      __syncthreads();
      buf ^= 1;
    }
  }

  // epilogue (R14-verified; fast_tanh): pre = acc + hsb[bb][p]
  const int p0 = w * 64 + col, p1 = p0 + 32;
  const float h0 = hsb[bb * NP_ + p0], h1 = hsb[bb * NP_ + p1];
  const float v0 = v[p0], v1 = v[p1];
#pragma unroll
  for (int mt = 0; mt < 2; mt++) {
#pragma unroll
    for (int r = 0; r < 16; r++) {
      float val = v0 * fast_tanh(acc[mt][0][r] + h0) + v1 * fast_tanh(acc[mt][1][r] + h1);
      val += __shfl_xor(val, 16);
      val += __shfl_xor(val, 8);
      val += __shfl_xor(val, 4);
      val += __shfl_xor(val, 2);
      val += __shfl_xor(val, 1);
      if (col == 0) {
        int row = mt * 32 + (r & 3) + 8 * (r >> 2) + 4 * half;
        pe[w][row] = val;
      }
    }
  }
  __syncthreads();
  if (tid < BM_) {
    float s = 0.f;
#pragma unroll
    for (int ww = 0; ww < 8; ww++) s += pe[ww][tid];
    e_out[(size_t)(R0 + tid)] = s;
  }
}

// ---------------------------------------------------------------------------
// Kernel D: softmax over L per batch (single e, R13 form).
// ---------------------------------------------------------------------------
__global__ __launch_bounds__(256) void k_softmax(const float* __restrict__ e,
                                                 float* __restrict__ w) {
  __shared__ float sh[L_];
  __shared__ float red[4];
  const int b = blockIdx.x, tid = threadIdx.x;
  const int lane = tid & 63, wv = tid >> 6;

  float m = -1e30f;
  for (int idx = tid; idx < L_; idx += 256) {
    float t = e[(size_t)b * L_ + idx];
    sh[idx] = t;
    m = fmaxf(m, t);
  }
  m = fmaxf(m, __shfl_down(m, 32));
  m = fmaxf(m, __shfl_down(m, 16));
  m = fmaxf(m, __shfl_down(m, 8));
  m = fmaxf(m, __shfl_down(m, 4));
  m = fmaxf(m, __shfl_down(m, 2));
  m = fmaxf(m, __shfl_down(m, 1));
  if (lane == 0) red[wv] = m;
  __syncthreads();
  m = fmaxf(fmaxf(red[0], red[1]), fmaxf(red[2], red[3]));
  __syncthreads();

  float s = 0.f;
  for (int idx = tid; idx < L_; idx += 256) {
    float t = expf(sh[idx] - m);
    sh[idx] = t;
    s += t;
  }
  s += __shfl_down(s, 32);
  s += __shfl_down(s, 16);
  s += __shfl_down(s, 8);
  s += __shfl_down(s, 4);
  s += __shfl_down(s, 2);
  s += __shfl_down(s, 1);
  if (lane == 0) red[wv] = s;
  __syncthreads();
  float total = red[0] + red[1] + red[2] + red[3];
  float inv = 1.f / total;
  for (int idx = tid; idx < L_; idx += 256)
    w[(size_t)b * L_ + idx] = sh[idx] * inv;
}

// ---------------------------------------------------------------------------
// Kernel E: context c_At[b][c] = sum_l w[b][l] * i[b][c][l]  (memory-bound)
// ---------------------------------------------------------------------------
__global__ __launch_bounds__(256) void k_context(const float* __restrict__ i_,
                                                 const float* __restrict__ w,
                                                 float* __restrict__ out) {
  __shared__ float red[4];
  const int b = blockIdx.y, c = blockIdx.x, tid = threadIdx.x;
  const int lane = tid & 63, wv = tid >> 6;
  const float4* row = (const float4*)(i_ + ((size_t)b * C_ + c) * L_);
  const float4* wr  = (const float4*)(w + (size_t)b * L_);
  float s = 0.f;
  for (int idx = tid; idx < L_ / 4; idx += 256) {
    float4 a = row[idx];
    float4 ww = wr[idx];
    s += a.x * ww.x + a.y * ww.y + a.z * ww.z + a.w * ww.w;
  }
  s += __shfl_down(s, 32);
  s += __shfl_down(s, 16);
  s += __shfl_down(s, 8);
  s += __shfl_down(s, 4);
  s += __shfl_down(s, 2);
  s += __shfl_down(s, 1);
  if (lane == 0) red[wv] = s;
  __syncthreads();
  if (tid == 0) out[(size_t)b * C_ + c] = red[0] + red[1] + red[2] + red[3];
}

// ---------------------------------------------------------------------------
extern "C" void kernel_launch(void* const* d_in, const int* in_sizes, int n_in,
                              void* d_out, int out_size, void* d_ws, size_t ws_size,
                              hipStream_t stream) {
  const float* i_      = (const float*)d_in[0];
  const float* hat_s_t = (const float*)d_in[1];
  const float* alpha   = (const float*)d_in[2];
  const float* conv_w  = (const float*)d_in[3];
  const float* conv_b  = (const float*)d_in[4];
  const float* Wa      = (const float*)d_in[5];
  const float* Wf      = (const float*)d_in[6];
  const float* Ws      = (const float*)d_in[7];
  const float* v       = (const float*)d_in[8];
  float* out = (float*)d_out;

  float* ws   = (float*)d_ws;
  float* hsb  = ws;                               // 32*512    f
  float* w2   = hsb + B_ * NP_;                   // 121*512   f
  float* e    = w2 + KK_ * NP_;                   // 32*3136   f
  float* anew = e + B_ * L_;                      // 32*3136   f
  unsigned short* Wbp = (unsigned short*)(anew + B_ * L_);  // 16*52*512 u16 = 832 KB
  // total ~2.1 MB workspace

  k_hsb<<<dim3(B_), dim3(256), 0, stream>>>(hat_s_t, Ws, conv_b, Wf, hsb);
  k_w2<<<dim3(KK_), dim3(256), 0, stream>>>(conv_w, Wf, w2);
  k_wb<<<dim3(KT_), dim3(512), 0, stream>>>(Wa, w2, Wbp);
  k_energy<<<dim3((B_ * L_) / BM_), dim3(512), 0, stream>>>(i_, alpha, Wbp, hsb, v, e);
  k_softmax<<<dim3(B_), dim3(256), 0, stream>>>(e, anew);
  k_context<<<dim3(C_, B_), dim3(256), 0, stream>>>(i_, anew, out);
}